// Round 10
// baseline (5366.832 us; speedup 1.0000x reference)
//
#include <hip/hip_runtime.h>

typedef __attribute__((ext_vector_type(8))) short s16x8;
typedef __attribute__((ext_vector_type(4))) float fx4;

static __device__ __forceinline__ unsigned short f2bf(float f){
  unsigned u = __float_as_uint(f);
  return (unsigned short)((u + 0x7fffu + ((u>>16)&1u)) >> 16);   // RNE
}
static __device__ __forceinline__ float bf2f(unsigned short s){
  return __uint_as_float(((unsigned)s)<<16);
}
// Two 16B LLC-point loads (sc0+sc1 = agent scope: bypass L1 AND L2, read the
// LLC). asm volatile + memory clobber => re-executed every poll iteration.
// R4-R9 lessons: cross-XCD data is only HW-coherent at the LLC; polled
// addresses must be re-read at the LLC each iteration; flag+data as separate
// objects costs two serialized LLC round trips -> validity lives IN the data
// (poison protocol).
static __device__ __forceinline__ void ld2_llc(const void* p0, const void* p1,
                                               uint4* o0, uint4* o1){
  uint4 a, b;
  asm volatile("global_load_dwordx4 %0, %2, off sc0 sc1\n\t"
               "global_load_dwordx4 %1, %3, off sc0 sc1\n\t"
               "s_waitcnt vmcnt(0)"
               : "=&v"(a), "=&v"(b) : "v"(p0), "v"(p1) : "memory");
  *o0 = a; *o1 = b;
}

// ---------------------------------------------------------------- W_out -> bf16
__global__ void k_cvt_wout(const float* __restrict__ w, unsigned short* __restrict__ o){
  int g = blockIdx.x*256 + threadIdx.x;
  int idx = g*4;
  float4 f = *(const float4*)(w + idx);
  unsigned u0 = (unsigned)f2bf(f.x) | ((unsigned)f2bf(f.y)<<16);
  unsigned u1 = (unsigned)f2bf(f.z) | ((unsigned)f2bf(f.w)<<16);
  *(uint2*)(o + idx) = make_uint2(u0, u1);
}

// ---------------------------------------------------------------- GEMM1: xp = x@W_ih^T + (b_ih+b_hh)
__global__ __launch_bounds__(256) void k_gemm_xp(
    const float* __restrict__ X, const float* __restrict__ Wih,
    const float* __restrict__ bih, const float* __restrict__ bhh,
    unsigned short* __restrict__ XP){
  __shared__ unsigned short As[128][40];
  __shared__ unsigned short Bs[128][40];
  const int bm = blockIdx.x, bn = blockIdx.y;
  const int tid = threadIdx.x, w = tid>>6, l = tid&63;
  const int wm = w>>1, wn = w&1;
  const int m0 = bm*128, n0 = bn*128;
  fx4 acc[4][4] = {};
  for (int kb = 0; kb < 512; kb += 32){
    #pragma unroll
    for (int q=0;q<4;q++){
      int f = tid + q*256;
      int row = f>>3, c4 = (f&7)*4;
      float4 v = *(const float4*)(X + (m0+row)*512 + kb + c4);
      unsigned u0 = (unsigned)f2bf(v.x) | ((unsigned)f2bf(v.y)<<16);
      unsigned u1 = (unsigned)f2bf(v.z) | ((unsigned)f2bf(v.w)<<16);
      *(uint2*)&As[row][c4] = make_uint2(u0,u1);
    }
    #pragma unroll
    for (int q=0;q<4;q++){
      int f = tid + q*256;
      int row = f>>3, c4 = (f&7)*4;
      float4 v = *(const float4*)(Wih + (n0+row)*512 + kb + c4);
      unsigned u0 = (unsigned)f2bf(v.x) | ((unsigned)f2bf(v.y)<<16);
      unsigned u1 = (unsigned)f2bf(v.z) | ((unsigned)f2bf(v.w)<<16);
      *(uint2*)&Bs[row][c4] = make_uint2(u0,u1);
    }
    __syncthreads();
    const int kbase = (l>>4)*8;
    s16x8 a[4], b[4];
    #pragma unroll
    for (int mt=0;mt<4;mt++) a[mt] = *(const s16x8*)&As[wm*64 + mt*16 + (l&15)][kbase];
    #pragma unroll
    for (int nt=0;nt<4;nt++) b[nt] = *(const s16x8*)&Bs[wn*64 + nt*16 + (l&15)][kbase];
    #pragma unroll
    for (int mt=0;mt<4;mt++)
      #pragma unroll
      for (int nt=0;nt<4;nt++)
        acc[mt][nt] = __builtin_amdgcn_mfma_f32_16x16x32_bf16(a[mt], b[nt], acc[mt][nt], 0,0,0);
    __syncthreads();
  }
  #pragma unroll
  for (int nt=0;nt<4;nt++){
    int n = n0 + wn*64 + nt*16 + (l&15);
    float bias = bih[n] + bhh[n];
    #pragma unroll
    for (int mt=0;mt<4;mt++){
      #pragma unroll
      for (int r=0;r<4;r++){
        int grow = m0 + wm*64 + mt*16 + (l>>4)*4 + r;   // = b*1024 + t
        int bb = grow >> 10, t = grow & 1023;
        XP[(t*64 + bb)*1024 + n] = f2bf(acc[mt][nt][r] + bias);
      }
    }
  }
}

// ---------------------------------------------------------------- recurrence
// DUAL-STREAM poison-poll. 32 WGs = 4 groups x 8 WGs(512thr). Group owns 16
// batch rows split into independent streams A (rows g*16..+7) and B (+8..+15);
// WG owns 128 cols; W_hh B-frags register-resident (128 VGPR/lane).
// Each iteration: phase A {poll/stage h_A[s-1] -> bar -> 32 MFMA -> tanh ->
// sc1 store h_A[s]}, then phase B likewise. While A's stores commit at the
// LLC and become poll-visible, the WG computes B -> the LLC handoff latency
// (commit+detect, the R9 critical path) hides behind the other stream's
// compute phase. Protocol per R9: HS pre-poisoned 0xFFFF (bf16 NaN, tanh can
// never produce it); write-once addresses; data self-announces via sc0+sc1
// poll loads. Placement-independent, flag-free, deadlock-impossible.
__global__ __launch_bounds__(512) void k_rnn(
    const float* __restrict__ Whh, const unsigned short* __restrict__ XP,
    unsigned short* __restrict__ HS){
  __shared__ unsigned short hldsA[8][1032];
  __shared__ unsigned short hldsB[8][1032];
  const int wg = blockIdx.x;
  const int gi = wg & 3;            // group (16 rows)
  const int gj = wg >> 2;           // col block (128 cols)
  const int biA = gi*16, biB = gi*16 + 8, cj = gj*128;
  const int tid = threadIdx.x, w = tid>>6, l = tid&63;
  const int kbase = (l>>4)*8;

  // --- W_hh slice as resident MFMA B-fragments (128 VGPR/lane) ---
  const int col = cj + w*16 + (l&15);
  s16x8 wf[32];
  #pragma unroll
  for (int kk=0; kk<32; kk++){
    const float* p = Whh + col*1024 + kk*32 + kbase;
    float4 v0 = *(const float4*)p;
    float4 v1 = *(const float4*)(p+4);
    s16x8 s;
    s[0]=(short)f2bf(v0.x); s[1]=(short)f2bf(v0.y); s[2]=(short)f2bf(v0.z); s[3]=(short)f2bf(v0.w);
    s[4]=(short)f2bf(v1.x); s[5]=(short)f2bf(v1.y); s[6]=(short)f2bf(v1.z); s[7]=(short)f2bf(v1.w);
    wf[kk]=s;
  }

  const int ecol = cj + w*16 + (l&15);
  const int srow = tid>>6, sc8 = (tid&63)*16;       // staging: thread owns (row, 32B)

  // --- step 0: h0 = tanh(xp_0) for both streams (16 rows x 128 cols) ---
  #pragma unroll
  for (int half=0; half<2; ++half){
    int bi = half ? biB : biA;
    int e = tid*2;
    int row = e>>7, c = e&127;
    unsigned short h0 = f2bf(tanhf(bf2f(XP[(bi+row)*1024 + cj + c])));
    unsigned short h1 = f2bf(tanhf(bf2f(XP[(bi+row)*1024 + cj + c + 1])));
    unsigned pk = (unsigned)h0 | ((unsigned)h1<<16);
    __hip_atomic_store((unsigned*)&HS[((bi+row)*1024 + 0)*1024 + cj + c], pk,
                       __ATOMIC_RELAXED, __HIP_MEMORY_SCOPE_AGENT);
  }

  for (int s=1; s<1024; ++s){
    // ================= phase A =================
    {
      float xv[4];
      if (l < 32){
        #pragma unroll
        for (int r=0;r<4;r++)
          xv[r] = bf2f(XP[(s*64 + biA + (l>>4)*4 + r)*1024 + ecol]);
      }
      // poison-poll + stage h_A[s-1]
      {
        const unsigned short* rowp = HS + ((biA+srow)*1024 + (s-1))*1024 + sc8;
        uint4 v0, v1;
        for(;;){
          ld2_llc(rowp, rowp+8, &v0, &v1);
          unsigned bad = 0u;
          #pragma unroll
          for (int j=0;j<4;j++){
            unsigned u = ((unsigned*)&v0)[j];
            bad |= (unsigned)((u & 0xFFFFu) == 0xFFFFu) | (unsigned)(u >= 0xFFFF0000u);
          }
          #pragma unroll
          for (int j=0;j<4;j++){
            unsigned u = ((unsigned*)&v1)[j];
            bad |= (unsigned)((u & 0xFFFFu) == 0xFFFFu) | (unsigned)(u >= 0xFFFF0000u);
          }
          if (!bad) break;
        }
        *(uint4*)&hldsA[srow][sc8]     = v0;
        *(uint4*)&hldsA[srow][sc8 + 8] = v1;
      }
      __syncthreads();
      const int arow = (l&15)&7;
      fx4 ac0 = {0.f,0.f,0.f,0.f}, ac1 = ac0, ac2 = ac0, ac3 = ac0;
      #pragma unroll
      for (int kk=0;kk<32;kk+=4){
        s16x8 a0 = *(const s16x8*)&hldsA[arow][(kk+0)*32 + kbase];
        s16x8 a1 = *(const s16x8*)&hldsA[arow][(kk+1)*32 + kbase];
        s16x8 a2 = *(const s16x8*)&hldsA[arow][(kk+2)*32 + kbase];
        s16x8 a3 = *(const s16x8*)&hldsA[arow][(kk+3)*32 + kbase];
        ac0 = __builtin_amdgcn_mfma_f32_16x16x32_bf16(a0, wf[kk+0], ac0, 0,0,0);
        ac1 = __builtin_amdgcn_mfma_f32_16x16x32_bf16(a1, wf[kk+1], ac1, 0,0,0);
        ac2 = __builtin_amdgcn_mfma_f32_16x16x32_bf16(a2, wf[kk+2], ac2, 0,0,0);
        ac3 = __builtin_amdgcn_mfma_f32_16x16x32_bf16(a3, wf[kk+3], ac3, 0,0,0);
      }
      fx4 acc = (ac0+ac1)+(ac2+ac3);
      if (l < 32){
        #pragma unroll
        for (int r=0;r<4;r++){
          int row = (l>>4)*4 + r;
          unsigned short hv = f2bf(tanhf(acc[r] + xv[r]));
          __hip_atomic_store(&HS[((biA+row)*1024 + s)*1024 + ecol], hv,
                             __ATOMIC_RELAXED, __HIP_MEMORY_SCOPE_AGENT);
        }
      }
      // stores drain via the next ld2_llc's vmcnt(0); commit+detect of A[s]
      // hides behind phase B's compute.
    }
    // ================= phase B =================
    {
      float xv[4];
      if (l < 32){
        #pragma unroll
        for (int r=0;r<4;r++)
          xv[r] = bf2f(XP[(s*64 + biB + (l>>4)*4 + r)*1024 + ecol]);
      }
      {
        const unsigned short* rowp = HS + ((biB+srow)*1024 + (s-1))*1024 + sc8;
        uint4 v0, v1;
        for(;;){
          ld2_llc(rowp, rowp+8, &v0, &v1);
          unsigned bad = 0u;
          #pragma unroll
          for (int j=0;j<4;j++){
            unsigned u = ((unsigned*)&v0)[j];
            bad |= (unsigned)((u & 0xFFFFu) == 0xFFFFu) | (unsigned)(u >= 0xFFFF0000u);
          }
          #pragma unroll
          for (int j=0;j<4;j++){
            unsigned u = ((unsigned*)&v1)[j];
            bad |= (unsigned)((u & 0xFFFFu) == 0xFFFFu) | (unsigned)(u >= 0xFFFF0000u);
          }
          if (!bad) break;
        }
        *(uint4*)&hldsB[srow][sc8]     = v0;
        *(uint4*)&hldsB[srow][sc8 + 8] = v1;
      }
      __syncthreads();
      const int arow = (l&15)&7;
      fx4 ac0 = {0.f,0.f,0.f,0.f}, ac1 = ac0, ac2 = ac0, ac3 = ac0;
      #pragma unroll
      for (int kk=0;kk<32;kk+=4){
        s16x8 a0 = *(const s16x8*)&hldsB[arow][(kk+0)*32 + kbase];
        s16x8 a1 = *(const s16x8*)&hldsB[arow][(kk+1)*32 + kbase];
        s16x8 a2 = *(const s16x8*)&hldsB[arow][(kk+2)*32 + kbase];
        s16x8 a3 = *(const s16x8*)&hldsB[arow][(kk+3)*32 + kbase];
        ac0 = __builtin_amdgcn_mfma_f32_16x16x32_bf16(a0, wf[kk+0], ac0, 0,0,0);
        ac1 = __builtin_amdgcn_mfma_f32_16x16x32_bf16(a1, wf[kk+1], ac1, 0,0,0);
        ac2 = __builtin_amdgcn_mfma_f32_16x16x32_bf16(a2, wf[kk+2], ac2, 0,0,0);
        ac3 = __builtin_amdgcn_mfma_f32_16x16x32_bf16(a3, wf[kk+3], ac3, 0,0,0);
      }
      fx4 acc = (ac0+ac1)+(ac2+ac3);
      if (l < 32){
        #pragma unroll
        for (int r=0;r<4;r++){
          int row = (l>>4)*4 + r;
          unsigned short hv = f2bf(tanhf(acc[r] + xv[r]));
          __hip_atomic_store(&HS[((biB+row)*1024 + s)*1024 + ecol], hv,
                             __ATOMIC_RELAXED, __HIP_MEMORY_SCOPE_AGENT);
        }
      }
    }
  }
}

// ---------------------------------------------------------------- GEMM2: out = hs@W_out^T + b_out
__global__ __launch_bounds__(512) void k_gemm_out(
    const unsigned short* __restrict__ HS, const unsigned short* __restrict__ WoutB,
    const float* __restrict__ bout, float* __restrict__ OUT){
  __shared__ unsigned short As[128][40];
  __shared__ unsigned short Bs[512][40];
  const int m0 = blockIdx.x*128;
  const int tid = threadIdx.x, w = tid>>6, l = tid&63;
  const int wm = w>>2, wn = w&3;
  fx4 acc[4][8] = {};
  for (int kb = 0; kb < 1024; kb += 32){
    {
      int row = tid>>2, c8 = (tid&3)*8;
      *(uint4*)&As[row][c8] = *(const uint4*)(HS + (m0+row)*1024 + kb + c8);
    }
    #pragma unroll
    for (int q=0;q<4;q++){
      int f = tid + q*512;
      int row = f>>2, c8 = (f&3)*8;
      *(uint4*)&Bs[row][c8] = *(const uint4*)(WoutB + row*1024 + kb + c8);
    }
    __syncthreads();
    const int kbase = (l>>4)*8;
    s16x8 a[4], b[8];
    #pragma unroll
    for (int mt=0;mt<4;mt++) a[mt] = *(const s16x8*)&As[wm*64 + mt*16 + (l&15)][kbase];
    #pragma unroll
    for (int nt=0;nt<8;nt++) b[nt] = *(const s16x8*)&Bs[wn*128 + nt*16 + (l&15)][kbase];
    #pragma unroll
    for (int mt=0;mt<4;mt++)
      #pragma unroll
      for (int nt=0;nt<8;nt++)
        acc[mt][nt] = __builtin_amdgcn_mfma_f32_16x16x32_bf16(a[mt], b[nt], acc[mt][nt], 0,0,0);
    __syncthreads();
  }
  #pragma unroll
  for (int nt=0;nt<8;nt++){
    int n = wn*128 + nt*16 + (l&15);
    float bias = bout[n];
    #pragma unroll
    for (int mt=0;mt<4;mt++){
      #pragma unroll
      for (int r=0;r<4;r++){
        int row = m0 + wm*64 + mt*16 + (l>>4)*4 + r;
        OUT[row*512 + n] = acc[mt][nt][r] + bias;
      }
    }
  }
}

// ---------------------------------------------------------------- launch
extern "C" void kernel_launch(void* const* d_in, const int* in_sizes, int n_in,
                              void* d_out, int out_size, void* d_ws, size_t ws_size,
                              hipStream_t stream){
  const float* x    = (const float*)d_in[0];
  const float* Wih  = (const float*)d_in[1];
  const float* Whh  = (const float*)d_in[2];
  const float* bih  = (const float*)d_in[3];
  const float* bhh  = (const float*)d_in[4];
  const float* Wout = (const float*)d_in[5];
  const float* bout = (const float*)d_in[6];

  const size_t XP_BYTES = 134217728ull;            // bf16 xp, [T][B][H]
  unsigned short* XP    = (unsigned short*)d_ws;
  unsigned short* WoutB = (unsigned short*)((char*)d_ws + XP_BYTES);
  unsigned short* HS    = (unsigned short*)d_out;  // hs bf16 lives in d_out
  float*          OUT   = (float*)d_out;

  k_cvt_wout<<<512, 256, 0, stream>>>(Wout, WoutB);
  dim3 g1(512, 8);
  k_gemm_xp<<<g1, 256, 0, stream>>>(x, Wih, bih, bhh, XP);
  // poison HS: 0xFF bytes -> every bf16 short is NaN (0xFFFF); tanh output
  // can never be NaN, so non-poison == final value (self-announcing data).
  hipMemsetAsync(HS, 0xFF, 134217728ull, stream);
  k_rnn<<<32, 512, 0, stream>>>(Whh, XP, HS);
  k_gemm_out<<<512, 512, 0, stream>>>(HS, WoutB, bout, OUT);
}